// Round 23
// baseline (186.015 us; speedup 1.0000x reference)
//
#include <hip/hip_runtime.h>
#include <math.h>

#define N_ROWS   65536
#define DIM      256
#define KCODES   1024
#define Q_SIZE   (N_ROWS * DIM)          // 16777216
#define OUT_LOSS Q_SIZE
#define OUT_PERP (Q_SIZE + 1)
#define OUT_IDX  (Q_SIZE + 2)

// flag threshold in scaled-score units (s' = 2^20 * d2-units). Same as r8 (passed).
#define TAUP 200.0f

// ws layout (bytes)
#define WS_LOSS   0        // double
#define WS_RCNT   8        // int
#define WS_E2     16       // float[1024]  original units
#define WS_E2P    4112     // float[1024]  scaled by 2^20
#define WS_COUNTS 8208     // int[1024]
#define WS_IDX    12304    // int[65536]
#define WS_RLIST  274448   // int[65536]
#define WS_ET     536592   // float[262144]   E^T fp32 (refine)
#define WS_P      1585168  // _Float16[262144] packed f16(1024*E), tile-linear
                           // (dead after k_main -> reused as hkA u64[65536])
#define WS_HKB    2109456  // u64[65536] half-1 keys (proven high-water 2633744)

typedef _Float16 half8 __attribute__((ext_vector_type(8)));
typedef _Float16 half4 __attribute__((ext_vector_type(4)));
typedef float    f32x4 __attribute__((ext_vector_type(4)));

#define ROWB 528    // LDS bytes per X row during A-load phase: 512 + 16 pad
#define RPB  128    // rows per block (r21-optimal: 2 blocks/CU, 8 waves/CU)

// k_main LDS: [0,49152) = X-staging region (phase 1/2) REUSED as 3-slot B
// rotation buffer [3][16384]; [49152,53248) e2p.
#define LDS_E2 49152

// ---------------------------------------------------------------------------
// prep: e2, e2p, Et (fp32 transpose, refine), packed P; zero accums.
// P layout (tile-linear): tile T = codes [T*32,T*32+32), 32 tiles.
// chunk c = nt*8+kk. o = ((T*16+c)*64+lane)*8+j; code = T*32+nt*16+(lane&15),
// d = (lane>>4)*8 + kk*32 + j. Each 1KB chunk lane-linear (GLL-ready).
// grid 1024 x 256
__global__ void k_prep(const float* __restrict__ E, float* __restrict__ e2,
                       float* __restrict__ e2p, float* __restrict__ Et,
                       _Float16* __restrict__ P,
                       int* __restrict__ counts, double* __restrict__ loss,
                       int* __restrict__ rcnt) {
    int b = blockIdx.x, t = threadIdx.x;
    __shared__ double red[256];
    float v = E[b * DIM + t];
    red[t] = (double)v * (double)v;

    {   // packed B-stream write (tile-linear)
        int o    = b * 256 + t;
        int j    = o & 7;
        int lane = (o >> 3) & 63;
        int c    = (o >> 9) & 15;      // chunk within tile
        int T    = o >> 13;            // tile 0..31
        int nt = c >> 3, kk = c & 7;
        int code = T * 32 + nt * 16 + (lane & 15);
        int d    = (lane >> 4) * 8 + kk * 32 + j;
        P[o] = (_Float16)(E[code * DIM + d] * 1024.0f);   // exact scaling, RN
    }

    __syncthreads();
    for (int s = 128; s > 0; s >>= 1) {
        if (t < s) red[t] += red[t + s];
        __syncthreads();
    }
    if (t == 0) { e2[b] = (float)red[0]; e2p[b] = (float)(red[0] * 1048576.0); }

    int o = b * 256 + t;
    int d = o >> 10, k = o & 1023;
    Et[o] = E[k * DIM + d];

    if (b < 4) counts[b * 256 + t] = 0;
    if (b == 0 && t == 0) { *loss = 0.0; *rcnt = 0; }
}

// ---------------------------------------------------------------------------
// main (r21-exact, best measured 70µs): A-in-registers GEMM, RPB=128,
// 3-slot B rotation with counted vmcnt + raw s_barrier pipeline.
// Numerics bit-identical to r8-r22.
// OCCUPANCY NOTE (r4-r7,r16,r22): no min-waves bound (spills); RPB=128 is
// the optimum of the bytes-per-row vs waves/CU trade (r20/r21/r22 curve).
// grid 512 x 256
__global__ void __launch_bounds__(256)
k_main(const float* __restrict__ X, const _Float16* __restrict__ P,
       const float* __restrict__ e2p,
       int* __restrict__ idx_ws, int* __restrict__ rlist,
       int* __restrict__ rcnt) {
    __shared__ __align__(16) char sAll[53248];
    const int tid  = threadIdx.x;
    const int wid  = tid >> 6;
    const int lane = tid & 63;
    const int c16  = lane & 15;
    const int kg   = lane >> 4;
    const int rb   = blockIdx.x * RPB;

    char* sX = sAll;
    char* sB = sAll;
    const float* sE2 = (const float*)(sAll + LDS_E2);

    ((f32x4*)(sAll + LDS_E2))[tid] = ((const f32x4*)e2p)[tid];

    // ---- A-load phase 1: rows 0..63 -> LDS f16, waves 0,1 grab A regs ----
    {
        const f32x4* Xg = (const f32x4*)(X + (size_t)rb * DIM);
        #pragma unroll
        for (int it = 0; it < 16; ++it) {
            int f = it * 256 + tid;
            int row = f >> 6, d4 = f & 63;
            f32x4 v = __builtin_nontemporal_load(&Xg[(size_t)row * 64 + d4]);
            half4 hh = {(_Float16)v[0], (_Float16)v[1], (_Float16)v[2], (_Float16)v[3]};
            *(half4*)(sX + row * ROWB + d4 * 8) = hh;
        }
    }
    __syncthreads();
    half8 ar[2][8];
    if (wid < 2) {
        #pragma unroll
        for (int mt = 0; mt < 2; ++mt)
            #pragma unroll
            for (int kk = 0; kk < 8; ++kk)
                ar[mt][kk] = *(const half8*)(sX + (wid * 32 + mt * 16 + c16) * ROWB
                                             + kk * 64 + kg * 16);
    }
    __syncthreads();
    {
        const f32x4* Xg = (const f32x4*)(X + (size_t)(rb + 64) * DIM);
        #pragma unroll
        for (int it = 0; it < 16; ++it) {
            int f = it * 256 + tid;
            int row = f >> 6, d4 = f & 63;
            f32x4 v = __builtin_nontemporal_load(&Xg[(size_t)row * 64 + d4]);
            half4 hh = {(_Float16)v[0], (_Float16)v[1], (_Float16)v[2], (_Float16)v[3]};
            *(half4*)(sX + row * ROWB + d4 * 8) = hh;
        }
    }
    __syncthreads();
    if (wid >= 2) {
        #pragma unroll
        for (int mt = 0; mt < 2; ++mt)
            #pragma unroll
            for (int kk = 0; kk < 8; ++kk)
                ar[mt][kk] = *(const half8*)(sX + ((wid - 2) * 32 + mt * 16 + c16) * ROWB
                                             + kk * 64 + kg * 16);
    }
    __syncthreads();

#define STAGE(T)                                                                             \
    {                                                                                        \
        const char* src_ = (const char*)P + (size_t)(T) * 16384 + (size_t)(wid * 4) * 1024   \
                           + (size_t)lane * 16;                                              \
        char* dst_ = sB + ((T) % 3) * 16384 + (wid * 4) * 1024;                              \
        __builtin_amdgcn_global_load_lds((const __attribute__((address_space(1))) unsigned int*)(src_),          \
                                         (__attribute__((address_space(3))) unsigned int*)(dst_), 16, 0, 0);     \
        __builtin_amdgcn_global_load_lds((const __attribute__((address_space(1))) unsigned int*)(src_ + 1024),   \
                                         (__attribute__((address_space(3))) unsigned int*)(dst_ + 1024), 16, 0, 0);\
        __builtin_amdgcn_global_load_lds((const __attribute__((address_space(1))) unsigned int*)(src_ + 2048),   \
                                         (__attribute__((address_space(3))) unsigned int*)(dst_ + 2048), 16, 0, 0);\
        __builtin_amdgcn_global_load_lds((const __attribute__((address_space(1))) unsigned int*)(src_ + 3072),   \
                                         (__attribute__((address_space(3))) unsigned int*)(dst_ + 3072), 16, 0, 0);\
    }
#define SB0 __builtin_amdgcn_sched_barrier(0)

    float tb1[8], tb2[8];
    int   ti1[8];
    #pragma unroll
    for (int i = 0; i < 8; ++i) { tb1[i] = 3.4e38f; tb2[i] = 3.4e38f; ti1[i] = 0; }

    f32x4 acc[2][2];

    STAGE(0); STAGE(1);
    SB0;

    #pragma unroll 2
    for (int T = 0; T < 32; ++T) {
        if (T <= 30) { asm volatile("s_waitcnt vmcnt(4)" ::: "memory"); }
        else         { asm volatile("s_waitcnt vmcnt(0)" ::: "memory"); }
        SB0;
        __builtin_amdgcn_s_barrier();
        SB0;
        if (T < 30) STAGE(T + 2);
        SB0;

        #pragma unroll
        for (int mt = 0; mt < 2; ++mt)
            #pragma unroll
            for (int nt = 0; nt < 2; ++nt) acc[mt][nt] = 0.0f;

        const char* bbuf = sB + (T % 3) * 16384 + (size_t)lane * 16;
        #pragma unroll
        for (int kk = 0; kk < 8; ++kk) {
            half8 b0 = *(const half8*)(bbuf + (0 * 8 + kk) * 1024);
            half8 b1 = *(const half8*)(bbuf + (1 * 8 + kk) * 1024);
            acc[0][0] = __builtin_amdgcn_mfma_f32_16x16x32_f16(ar[0][kk], b0, acc[0][0], 0, 0, 0);
            acc[0][1] = __builtin_amdgcn_mfma_f32_16x16x32_f16(ar[0][kk], b1, acc[0][1], 0, 0, 0);
            acc[1][0] = __builtin_amdgcn_mfma_f32_16x16x32_f16(ar[1][kk], b0, acc[1][0], 0, 0, 0);
            acc[1][1] = __builtin_amdgcn_mfma_f32_16x16x32_f16(ar[1][kk], b1, acc[1][1], 0, 0, 0);
        }

        #pragma unroll
        for (int nt = 0; nt < 2; ++nt) {
            const int code = T * 32 + nt * 16 + c16;
            const float e2v = sE2[code];
            #pragma unroll
            for (int mt = 0; mt < 2; ++mt)
                #pragma unroll
                for (int r = 0; r < 4; ++r) {
                    float sc = fmaf(-2048.0f, acc[mt][nt][r], e2v);
                    int ix = mt * 4 + r;
                    tb2[ix] = __builtin_amdgcn_fmed3f(tb1[ix], tb2[ix], sc);
                    bool lt = sc < tb1[ix];
                    tb1[ix] = lt ? sc : tb1[ix];
                    ti1[ix] = lt ? code : ti1[ix];
                }
        }
        SB0;
    }
#undef STAGE
#undef SB0

    #pragma unroll
    for (int ix = 0; ix < 8; ++ix) {
        float v1 = tb1[ix], v2 = tb2[ix];
        int   j1 = ti1[ix];
        #pragma unroll
        for (int m = 1; m < 16; m <<= 1) {
            float ov1 = __shfl_xor(v1, m, 64);
            int   oj1 = __shfl_xor(j1, m, 64);
            float ov2 = __shfl_xor(v2, m, 64);
            bool take = (ov1 < v1) || (ov1 == v1 && oj1 < j1);
            float losr = take ? v1 : ov1;
            v1 = take ? ov1 : v1;
            j1 = take ? oj1 : j1;
            v2 = fminf(fminf(v2, ov2), losr);
        }
        tb1[ix] = v1; tb2[ix] = v2; ti1[ix] = j1;
    }
    if (c16 == 0) {
        #pragma unroll
        for (int ix = 0; ix < 8; ++ix) {
            int row = wid * 32 + (ix >> 2) * 16 + kg * 4 + (ix & 3);
            int g = rb + row;
            idx_ws[g] = ti1[ix];
            if (tb2[ix] - tb1[ix] < TAUP) {
                int slot = atomicAdd(rcnt, 1);
                rlist[slot] = g;
            }
        }
    }
}

// ---------------------------------------------------------------------------
// refine-half (r23): unit = (8 flagged rows) x (512-code half). 2x busy
// blocks vs 4-row (r15: 58.7µs) and Et bytes/row halved (256->128KB).
// Thread t owns codes {half*512+t, half*512+256+t} for 8 rows: 16 fp64 accs
// (32 VGPRs, no spill under (256,1)). Per (row,code): M = fl32(SERIAL fp64
// dot, d ascending — identical to all passing rounds); d2 = fmaf(-2,M,x2+e2).
// Half-winner written as packed key (ordered-d2)<<32|idx to hkA/hkB — no
// atomics; k_rmerge takes min (lexicographic = numpy argmin tie-break).
// grid 1024 x 256
__launch_bounds__(256, 1)
__global__ void k_rhalf(const float* __restrict__ X, const float* __restrict__ Et,
                        const float* __restrict__ e2,
                        const int* __restrict__ rlist, const int* __restrict__ rcnt,
                        unsigned long long* __restrict__ hkA,
                        unsigned long long* __restrict__ hkB) {
    __shared__ float xs[8][256];
    __shared__ float sbv[8][256];
    __shared__ int   sbi[8][256];
    __shared__ float x2s[8];
    __shared__ int   rows[8];
    const int cnt = *rcnt;
    const int t = threadIdx.x;
    const int ngroups = (cnt + 7) >> 3;
    for (int uid = blockIdx.x; uid < 2 * ngroups; uid += gridDim.x) {
        const int half = uid & 1;
        const int g8   = uid >> 1;
        __syncthreads();
        if (t < 8) {
            int e = g8 * 8 + t;
            rows[t] = rlist[e < cnt ? e : (cnt - 1)];
        }
        __syncthreads();
        // stage 8 rows of X (512 float4 slots)
        #pragma unroll
        for (int i = 0; i < 2; ++i) {
            int idx = t + i * 256;
            int r = idx >> 6, c4 = idx & 63;
            ((float4*)xs[r])[c4] = ((const float4*)(X + (size_t)rows[r] * DIM))[c4];
        }
        __syncthreads();
        // x2_32 per row (fp64 serial over d, fl32) — same as passing rounds
        if (t < 8) {
            double s = 0.0;
            for (int d = 0; d < DIM; ++d) { double xv = (double)xs[t][d]; s += xv * xv; }
            x2s[t] = (float)s;
        }
        __syncthreads();

        const int cA = half * 512 + t;        // first owned code
        const int cB = cA + 256;              // second owned code
        double a0[8], a1[8];
        #pragma unroll
        for (int r = 0; r < 8; ++r) { a0[r] = 0.0; a1[r] = 0.0; }
        #pragma unroll 4
        for (int d = 0; d < DIM; ++d) {
            double e0 = (double)Et[d * KCODES + cA];
            double e1 = (double)Et[d * KCODES + cB];
            #pragma unroll
            for (int r = 0; r < 8; ++r) {
                double xv = (double)xs[r][d];
                a0[r] += xv * e0;
                a1[r] += xv * e1;
            }
        }

        const float eA = e2[cA], eB = e2[cB];
        #pragma unroll
        for (int r = 0; r < 8; ++r) {
            float x2 = x2s[r];
            float best; int bk;
            float d2a = fmaf(-2.f, (float)a0[r], x2 + eA);
            float d2b = fmaf(-2.f, (float)a1[r], x2 + eB);
            if (d2a <= d2b) { best = d2a; bk = cA; }   // cA < cB: ties -> cA
            else            { best = d2b; bk = cB; }
            sbv[r][t] = best; sbi[r][t] = bk;
        }
        __syncthreads();
        // reduce: wave w handles rows 2w, 2w+1
        {
            const int w = t >> 6, lane = t & 63;
            #pragma unroll
            for (int i = 0; i < 2; ++i) {
                int r = w * 2 + i;
                float v = sbv[r][lane];     int id = sbi[r][lane];
                #pragma unroll
                for (int c = 1; c < 4; ++c) {
                    float ov = sbv[r][lane + 64 * c]; int oi = sbi[r][lane + 64 * c];
                    if (ov < v || (ov == v && oi < id)) { v = ov; id = oi; }
                }
                #pragma unroll
                for (int m = 1; m < 64; m <<= 1) {
                    float ov = __shfl_xor(v, m, 64);
                    int   oi = __shfl_xor(id, m, 64);
                    if (ov < v || (ov == v && oi < id)) { v = ov; id = oi; }
                }
                int e = g8 * 8 + r;
                if (lane == 0 && e < cnt) {
                    unsigned int u = __float_as_uint(v);
                    u = (u & 0x80000000u) ? ~u : (u | 0x80000000u);
                    unsigned long long key = ((unsigned long long)u << 32) | (unsigned int)id;
                    (half ? hkB : hkA)[e] = key;
                }
            }
        }
    }
}

// ---------------------------------------------------------------------------
// rmerge: winner = min(halves) per flagged row. grid 256 x 256
__global__ void k_rmerge(const int* __restrict__ rlist, const int* __restrict__ rcnt,
                         const unsigned long long* __restrict__ hkA,
                         const unsigned long long* __restrict__ hkB,
                         int* __restrict__ idx_ws) {
    int e = blockIdx.x * 256 + threadIdx.x;
    if (e < *rcnt) {
        unsigned long long ka = hkA[e], kb = hkB[e];
        unsigned long long k = ka < kb ? ka : kb;
        idx_ws[rlist[e]] = (int)(k & 0xFFFFFFFFull);
    }
}

// ---------------------------------------------------------------------------
// out: quantized rows, index output, loss, histogram. One fp64 atomic/block.
// grid 1024 x 256
__launch_bounds__(256)
__global__ void k_out(const float* __restrict__ X, const float* __restrict__ E,
                      const int* __restrict__ idx_ws, float* __restrict__ out,
                      int* __restrict__ counts, double* __restrict__ loss) {
    const int tid = threadIdx.x;
    const int w = tid >> 6, lane = tid & 63;
    const int rbase = blockIdx.x * 64;
    double ls = 0.0;
    #pragma unroll 4
    for (int it = 0; it < 16; ++it) {
        const int row = rbase + it * 4 + w;
        const int k = idx_ws[row];
        float4 q = ((const float4*)(E + (size_t)k * DIM))[lane];
        float4 x = ((const float4*)(X + (size_t)row * DIM))[lane];
        ((float4*)(out + (size_t)row * DIM))[lane] = q;
        double d0 = (double)q.x - (double)x.x;
        double d1 = (double)q.y - (double)x.y;
        double d2 = (double)q.z - (double)x.z;
        double d3 = (double)q.w - (double)x.w;
        ls += d0 * d0 + d1 * d1 + d2 * d2 + d3 * d3;
        if (lane == 0) {
            atomicAdd(&counts[k], 1);
            out[OUT_IDX + row] = (float)k;
        }
    }
    __shared__ double red[256];
    red[tid] = ls;
    __syncthreads();
    for (int s = 128; s > 0; s >>= 1) {
        if (tid < s) red[tid] += red[tid + s];
        __syncthreads();
    }
    if (tid == 0) atomicAdd(loss, red[0]);
}

// ---------------------------------------------------------------------------
// fin: scalars
__global__ void k_fin(const int* __restrict__ counts, const double* __restrict__ loss,
                      float* __restrict__ out) {
    int t = threadIdx.x;
    __shared__ double red[256];
    double h = 0.0;
    #pragma unroll
    for (int i = 0; i < 4; ++i) {
        double p = (double)counts[t + i * 256] / (double)N_ROWS;
        h += p * log(p + 1e-10);
    }
    red[t] = h;
    __syncthreads();
    for (int s = 128; s > 0; s >>= 1) {
        if (t < s) red[t] += red[t + s];
        __syncthreads();
    }
    if (t == 0) {
        out[OUT_PERP] = (float)exp(-red[0]);
        out[OUT_LOSS] = (float)((*loss) / (double)Q_SIZE * 1.25);
    }
}

// ---------------------------------------------------------------------------
extern "C" void kernel_launch(void* const* d_in, const int* in_sizes, int n_in,
                              void* d_out, int out_size, void* d_ws, size_t ws_size,
                              hipStream_t stream) {
    (void)in_sizes; (void)n_in; (void)out_size; (void)ws_size;
    const float* X = (const float*)d_in[0];
    const float* E = (const float*)d_in[1];
    float* out = (float*)d_out;
    char* ws = (char*)d_ws;

    double*             loss   = (double*)(ws + WS_LOSS);
    int*                rcnt   = (int*)(ws + WS_RCNT);
    float*              e2     = (float*)(ws + WS_E2);
    float*              e2p    = (float*)(ws + WS_E2P);
    int*                counts = (int*)(ws + WS_COUNTS);
    int*                idx_ws = (int*)(ws + WS_IDX);
    int*                rlist  = (int*)(ws + WS_RLIST);
    float*              Et     = (float*)(ws + WS_ET);
    _Float16*           Pp     = (_Float16*)(ws + WS_P);
    unsigned long long* hkA    = (unsigned long long*)(ws + WS_P);    // reuse P
    unsigned long long* hkB    = (unsigned long long*)(ws + WS_HKB);

    k_prep<<<1024, 256, 0, stream>>>(E, e2, e2p, Et, Pp, counts, loss, rcnt);
    k_main<<<N_ROWS / RPB, 256, 0, stream>>>(X, Pp, e2p, idx_ws, rlist, rcnt);
    k_rhalf<<<1024, 256, 0, stream>>>(X, Et, e2, rlist, rcnt, hkA, hkB);
    k_rmerge<<<256, 256, 0, stream>>>(rlist, rcnt, hkA, hkB, idx_ws);
    k_out<<<1024, 256, 0, stream>>>(X, E, idx_ws, out, counts, loss);
    k_fin<<<1, 256, 0, stream>>>(counts, loss, out);
}

// Round 24
// 170.830 us; speedup vs baseline: 1.0889x; 1.0889x over previous
//
#include <hip/hip_runtime.h>
#include <math.h>

#define N_ROWS   65536
#define DIM      256
#define KCODES   1024
#define Q_SIZE   (N_ROWS * DIM)          // 16777216
#define OUT_LOSS Q_SIZE
#define OUT_PERP (Q_SIZE + 1)
#define OUT_IDX  (Q_SIZE + 2)

// flag threshold in scaled-score units (s' = 2^20 * d2-units). Same as r8 (passed).
#define TAUP 200.0f
// prune candidate margin (original d2 units): winner lies within 5e-5 of the
// approx min (fp32-dot error <= ~2.5e-5 both sides); 1.5e-4 = 3x safety.
#define MARGIN 1.5e-4f
#define NCAP   16384

// ws layout (bytes)
#define WS_LOSS   0        // double
#define WS_RCNT   8        // int
#define WS_E2     16       // float[1024]  original units
#define WS_E2P    4112     // float[1024]  scaled by 2^20
#define WS_COUNTS 8208     // int[1024]
#define WS_IDX    12304    // int[65536]
#define WS_RLIST  274448   // int[65536]
#define WS_ET     536592   // float[262144]   E^T fp32 (prune)
#define WS_P      1585168  // _Float16[262144] packed f16(1024*E), tile-linear
// P region is dead after k_main -> reused for refine scratch:
#define WS_NCAND  1585168  // int[16384]
#define WS_PK     1650704  // u64[16384]
#define WS_CAND   1781776  // int[16384*8]  (ends 2306064 <= proven 2633744)

typedef _Float16 half8 __attribute__((ext_vector_type(8)));
typedef _Float16 half4 __attribute__((ext_vector_type(4)));
typedef float    f32x4 __attribute__((ext_vector_type(4)));

#define ROWB 528    // LDS bytes per X row during A-load phase: 512 + 16 pad
#define RPB  128    // rows per block (r21-optimal: 2 blocks/CU)

// k_main LDS: [0,49152) X-staging REUSED as 3-slot B rotation; [49152,53248) e2p.
#define LDS_E2 49152

// ---------------------------------------------------------------------------
// prep: e2, e2p, Et (fp32 transpose), packed P; zero accums.
// grid 1024 x 256
__global__ void k_prep(const float* __restrict__ E, float* __restrict__ e2,
                       float* __restrict__ e2p, float* __restrict__ Et,
                       _Float16* __restrict__ P,
                       int* __restrict__ counts, double* __restrict__ loss,
                       int* __restrict__ rcnt) {
    int b = blockIdx.x, t = threadIdx.x;
    __shared__ double red[256];
    float v = E[b * DIM + t];
    red[t] = (double)v * (double)v;

    {   // packed B-stream write (tile-linear)
        int o    = b * 256 + t;
        int j    = o & 7;
        int lane = (o >> 3) & 63;
        int c    = (o >> 9) & 15;
        int T    = o >> 13;
        int nt = c >> 3, kk = c & 7;
        int code = T * 32 + nt * 16 + (lane & 15);
        int d    = (lane >> 4) * 8 + kk * 32 + j;
        P[o] = (_Float16)(E[code * DIM + d] * 1024.0f);   // exact scaling, RN
    }

    __syncthreads();
    for (int s = 128; s > 0; s >>= 1) {
        if (t < s) red[t] += red[t + s];
        __syncthreads();
    }
    if (t == 0) { e2[b] = (float)red[0]; e2p[b] = (float)(red[0] * 1048576.0); }

    int o = b * 256 + t;
    int d = o >> 10, k = o & 1023;
    Et[o] = E[k * DIM + d];

    if (b < 4) counts[b * 256 + t] = 0;
    if (b == 0 && t == 0) { *loss = 0.0; *rcnt = 0; }
}

// ---------------------------------------------------------------------------
// main (r21-exact, best measured 70µs): A-in-registers GEMM, RPB=128,
// 3-slot B rotation with counted vmcnt + raw s_barrier pipeline.
// Numerics bit-identical to r8-r23.
// grid 512 x 256
__global__ void __launch_bounds__(256)
k_main(const float* __restrict__ X, const _Float16* __restrict__ P,
       const float* __restrict__ e2p,
       int* __restrict__ idx_ws, int* __restrict__ rlist,
       int* __restrict__ rcnt) {
    __shared__ __align__(16) char sAll[53248];
    const int tid  = threadIdx.x;
    const int wid  = tid >> 6;
    const int lane = tid & 63;
    const int c16  = lane & 15;
    const int kg   = lane >> 4;
    const int rb   = blockIdx.x * RPB;

    char* sX = sAll;
    char* sB = sAll;
    const float* sE2 = (const float*)(sAll + LDS_E2);

    ((f32x4*)(sAll + LDS_E2))[tid] = ((const f32x4*)e2p)[tid];

    {
        const f32x4* Xg = (const f32x4*)(X + (size_t)rb * DIM);
        #pragma unroll
        for (int it = 0; it < 16; ++it) {
            int f = it * 256 + tid;
            int row = f >> 6, d4 = f & 63;
            f32x4 v = __builtin_nontemporal_load(&Xg[(size_t)row * 64 + d4]);
            half4 hh = {(_Float16)v[0], (_Float16)v[1], (_Float16)v[2], (_Float16)v[3]};
            *(half4*)(sX + row * ROWB + d4 * 8) = hh;
        }
    }
    __syncthreads();
    half8 ar[2][8];
    if (wid < 2) {
        #pragma unroll
        for (int mt = 0; mt < 2; ++mt)
            #pragma unroll
            for (int kk = 0; kk < 8; ++kk)
                ar[mt][kk] = *(const half8*)(sX + (wid * 32 + mt * 16 + c16) * ROWB
                                             + kk * 64 + kg * 16);
    }
    __syncthreads();
    {
        const f32x4* Xg = (const f32x4*)(X + (size_t)(rb + 64) * DIM);
        #pragma unroll
        for (int it = 0; it < 16; ++it) {
            int f = it * 256 + tid;
            int row = f >> 6, d4 = f & 63;
            f32x4 v = __builtin_nontemporal_load(&Xg[(size_t)row * 64 + d4]);
            half4 hh = {(_Float16)v[0], (_Float16)v[1], (_Float16)v[2], (_Float16)v[3]};
            *(half4*)(sX + row * ROWB + d4 * 8) = hh;
        }
    }
    __syncthreads();
    if (wid >= 2) {
        #pragma unroll
        for (int mt = 0; mt < 2; ++mt)
            #pragma unroll
            for (int kk = 0; kk < 8; ++kk)
                ar[mt][kk] = *(const half8*)(sX + ((wid - 2) * 32 + mt * 16 + c16) * ROWB
                                             + kk * 64 + kg * 16);
    }
    __syncthreads();

#define STAGE(T)                                                                             \
    {                                                                                        \
        const char* src_ = (const char*)P + (size_t)(T) * 16384 + (size_t)(wid * 4) * 1024   \
                           + (size_t)lane * 16;                                              \
        char* dst_ = sB + ((T) % 3) * 16384 + (wid * 4) * 1024;                              \
        __builtin_amdgcn_global_load_lds((const __attribute__((address_space(1))) unsigned int*)(src_),          \
                                         (__attribute__((address_space(3))) unsigned int*)(dst_), 16, 0, 0);     \
        __builtin_amdgcn_global_load_lds((const __attribute__((address_space(1))) unsigned int*)(src_ + 1024),   \
                                         (__attribute__((address_space(3))) unsigned int*)(dst_ + 1024), 16, 0, 0);\
        __builtin_amdgcn_global_load_lds((const __attribute__((address_space(1))) unsigned int*)(src_ + 2048),   \
                                         (__attribute__((address_space(3))) unsigned int*)(dst_ + 2048), 16, 0, 0);\
        __builtin_amdgcn_global_load_lds((const __attribute__((address_space(1))) unsigned int*)(src_ + 3072),   \
                                         (__attribute__((address_space(3))) unsigned int*)(dst_ + 3072), 16, 0, 0);\
    }
#define SB0 __builtin_amdgcn_sched_barrier(0)

    float tb1[8], tb2[8];
    int   ti1[8];
    #pragma unroll
    for (int i = 0; i < 8; ++i) { tb1[i] = 3.4e38f; tb2[i] = 3.4e38f; ti1[i] = 0; }

    f32x4 acc[2][2];

    STAGE(0); STAGE(1);
    SB0;

    #pragma unroll 2
    for (int T = 0; T < 32; ++T) {
        if (T <= 30) { asm volatile("s_waitcnt vmcnt(4)" ::: "memory"); }
        else         { asm volatile("s_waitcnt vmcnt(0)" ::: "memory"); }
        SB0;
        __builtin_amdgcn_s_barrier();
        SB0;
        if (T < 30) STAGE(T + 2);
        SB0;

        #pragma unroll
        for (int mt = 0; mt < 2; ++mt)
            #pragma unroll
            for (int nt = 0; nt < 2; ++nt) acc[mt][nt] = 0.0f;

        const char* bbuf = sB + (T % 3) * 16384 + (size_t)lane * 16;
        #pragma unroll
        for (int kk = 0; kk < 8; ++kk) {
            half8 b0 = *(const half8*)(bbuf + (0 * 8 + kk) * 1024);
            half8 b1 = *(const half8*)(bbuf + (1 * 8 + kk) * 1024);
            acc[0][0] = __builtin_amdgcn_mfma_f32_16x16x32_f16(ar[0][kk], b0, acc[0][0], 0, 0, 0);
            acc[0][1] = __builtin_amdgcn_mfma_f32_16x16x32_f16(ar[0][kk], b1, acc[0][1], 0, 0, 0);
            acc[1][0] = __builtin_amdgcn_mfma_f32_16x16x32_f16(ar[1][kk], b0, acc[1][0], 0, 0, 0);
            acc[1][1] = __builtin_amdgcn_mfma_f32_16x16x32_f16(ar[1][kk], b1, acc[1][1], 0, 0, 0);
        }

        #pragma unroll
        for (int nt = 0; nt < 2; ++nt) {
            const int code = T * 32 + nt * 16 + c16;
            const float e2v = sE2[code];
            #pragma unroll
            for (int mt = 0; mt < 2; ++mt)
                #pragma unroll
                for (int r = 0; r < 4; ++r) {
                    float sc = fmaf(-2048.0f, acc[mt][nt][r], e2v);
                    int ix = mt * 4 + r;
                    tb2[ix] = __builtin_amdgcn_fmed3f(tb1[ix], tb2[ix], sc);
                    bool lt = sc < tb1[ix];
                    tb1[ix] = lt ? sc : tb1[ix];
                    ti1[ix] = lt ? code : ti1[ix];
                }
        }
        SB0;
    }
#undef STAGE
#undef SB0

    #pragma unroll
    for (int ix = 0; ix < 8; ++ix) {
        float v1 = tb1[ix], v2 = tb2[ix];
        int   j1 = ti1[ix];
        #pragma unroll
        for (int m = 1; m < 16; m <<= 1) {
            float ov1 = __shfl_xor(v1, m, 64);
            int   oj1 = __shfl_xor(j1, m, 64);
            float ov2 = __shfl_xor(v2, m, 64);
            bool take = (ov1 < v1) || (ov1 == v1 && oj1 < j1);
            float losr = take ? v1 : ov1;
            v1 = take ? ov1 : v1;
            j1 = take ? oj1 : j1;
            v2 = fminf(fminf(v2, ov2), losr);
        }
        tb1[ix] = v1; tb2[ix] = v2; ti1[ix] = j1;
    }
    if (c16 == 0) {
        #pragma unroll
        for (int ix = 0; ix < 8; ++ix) {
            int row = wid * 32 + (ix >> 2) * 16 + kg * 4 + (ix & 3);
            int g = rb + row;
            idx_ws[g] = ti1[ix];
            if (tb2[ix] - tb1[ix] < TAUP) {
                int slot = atomicAdd(rcnt, 1);
                rlist[slot] = g;
            }
        }
    }
}

// ---------------------------------------------------------------------------
// rprune (r24): fp32 candidate generation for flagged rows. Structure = r15
// refine (4 rows/unit, grid 1024) but fp32 accumulation — r23 PMC proved
// refine was fp64-FMA-throughput-bound (1.3 GFLOP fp64 @ ~17TF ceiling);
// fp32 runs at 8x that rate. Per row: approx d2 for all 1024 codes
// (error <= ~2.5e-5), collect codes with d2 < min + MARGIN (winner provably
// inside; typically ~2/row). Exact fp64 work then drops ~100x.
// grid 1024 x 256
__launch_bounds__(256, 1)
__global__ void k_rprune(const float* __restrict__ X, const float* __restrict__ Et,
                         const float* __restrict__ e2,
                         const int* __restrict__ rlist, const int* __restrict__ rcnt,
                         int* __restrict__ ncand, int* __restrict__ cand,
                         unsigned long long* __restrict__ pk) {
    __shared__ float xs[4][256];
    __shared__ float sbv[4][256];
    __shared__ int   lcnt[4];
    __shared__ float x2s[4];
    __shared__ int   rows[4];
    const int cnt0 = *rcnt;
    const int cnt = cnt0 < NCAP ? cnt0 : NCAP;
    const int t = threadIdx.x;
    for (int base = blockIdx.x * 4; base < cnt; base += gridDim.x * 4) {
        __syncthreads();
        if (t < 4) {
            int e = base + t;
            rows[t] = rlist[e < cnt ? e : (cnt - 1)];
            lcnt[t] = 0;
            if (e < cnt) pk[e] = 0xFFFFFFFFFFFFFFFFull;
        }
        __syncthreads();
        ((float4*)xs[t >> 6])[t & 63] =
            ((const float4*)(X + (size_t)rows[t >> 6] * DIM))[t & 63];
        __syncthreads();
        if (t < 4) {
            double s = 0.0;
            for (int d = 0; d < DIM; ++d) { double xv = (double)xs[t][d]; s += xv * xv; }
            x2s[t] = (float)s;
        }
        __syncthreads();

        float a0[4], a1[4], a2[4], a3[4];
        #pragma unroll
        for (int r = 0; r < 4; ++r) { a0[r] = 0.f; a1[r] = 0.f; a2[r] = 0.f; a3[r] = 0.f; }
        #pragma unroll 4
        for (int d = 0; d < DIM; ++d) {
            float e0 = Et[d * KCODES + t];
            float e1 = Et[d * KCODES + 256 + t];
            float e2d = Et[d * KCODES + 512 + t];
            float e3 = Et[d * KCODES + 768 + t];
            #pragma unroll
            for (int r = 0; r < 4; ++r) {
                float xv = xs[r][d];
                a0[r] = fmaf(xv, e0, a0[r]);
                a1[r] = fmaf(xv, e1, a1[r]);
                a2[r] = fmaf(xv, e2d, a2[r]);
                a3[r] = fmaf(xv, e3, a3[r]);
            }
        }

        // per-code approx d2; per-row min via LDS tree
        float d2v[4][4];
        const float eA = e2[t], eB = e2[256 + t], eC = e2[512 + t], eD = e2[768 + t];
        #pragma unroll
        for (int r = 0; r < 4; ++r) {
            float x2 = x2s[r];
            d2v[r][0] = fmaf(-2.f, a0[r], x2 + eA);
            d2v[r][1] = fmaf(-2.f, a1[r], x2 + eB);
            d2v[r][2] = fmaf(-2.f, a2[r], x2 + eC);
            d2v[r][3] = fmaf(-2.f, a3[r], x2 + eD);
            sbv[r][t] = fminf(fminf(d2v[r][0], d2v[r][1]), fminf(d2v[r][2], d2v[r][3]));
        }
        __syncthreads();
        for (int s = 128; s > 0; s >>= 1) {
            if (t < s) {
                #pragma unroll
                for (int r = 0; r < 4; ++r)
                    sbv[r][t] = fminf(sbv[r][t], sbv[r][t + s]);
            }
            __syncthreads();
        }
        // collect candidates within MARGIN of per-row min
        #pragma unroll
        for (int r = 0; r < 4; ++r) {
            int e = base + r;
            if (e < cnt) {
                float thr = sbv[r][0] + MARGIN;
                #pragma unroll
                for (int seg = 0; seg < 4; ++seg) {
                    if (d2v[r][seg] < thr) {
                        int slot = atomicAdd(&lcnt[r], 1);
                        if (slot < 8) cand[e * 8 + slot] = seg * 256 + t;
                    }
                }
            }
        }
        __syncthreads();
        if (t < 4 && base + t < cnt) ncand[base + t] = lcnt[t];
    }
}

// ---------------------------------------------------------------------------
// rexact: exact reference-fp32 replication on candidates only. One thread per
// (e, j): serial fp64 dot + sum-of-squares, d ascending (identical order to
// all passing rounds), fl32, d2 = fmaf(-2,M,x2+e2). Lexicographic winner via
// packed-key atomicMin (= numpy argmin tie-break). Overflow (>8 cands,
// statistically unreachable): j==0 thread sweeps all 1024 codes serially.
// grid 512 x 256
__global__ void k_rexact(const float* __restrict__ X, const float* __restrict__ E,
                         const float* __restrict__ e2,
                         const int* __restrict__ rlist, const int* __restrict__ rcnt,
                         const int* __restrict__ ncand, const int* __restrict__ cand,
                         unsigned long long* __restrict__ pk) {
    int idx = blockIdx.x * 256 + threadIdx.x;
    int e = idx >> 3, j = idx & 7;
    const int cnt0 = *rcnt;
    const int cnt = cnt0 < NCAP ? cnt0 : NCAP;
    if (e >= cnt) return;
    int nc = ncand[e];
    int row = rlist[e];
    const float* xp = X + (size_t)row * DIM;

    if (nc > 8) {
        if (j != 0) return;
        // full serial sweep (never triggers; correctness backstop)
        double xacc = 0.0;
        for (int d = 0; d < DIM; ++d) { double xv = (double)xp[d]; xacc += xv * xv; }
        float x2 = (float)xacc;
        float best = 3.4e38f; int bk = 0;
        for (int c = 0; c < KCODES; ++c) {
            const float* ep = E + (size_t)c * DIM;
            double acc = 0.0;
            for (int d = 0; d < DIM; ++d) acc += (double)xp[d] * (double)ep[d];
            float d2 = fmaf(-2.f, (float)acc, x2 + e2[c]);
            if (d2 < best) { best = d2; bk = c; }
        }
        unsigned int u = __float_as_uint(best);
        u = (u & 0x80000000u) ? ~u : (u | 0x80000000u);
        atomicMin(&pk[e], ((unsigned long long)u << 32) | (unsigned int)bk);
        return;
    }
    if (j >= nc) return;
    int c = cand[e * 8 + j];
    const float* ep = E + (size_t)c * DIM;
    double acc = 0.0, xacc = 0.0;
    #pragma unroll 4
    for (int d = 0; d < DIM; ++d) {
        double xv = (double)xp[d];
        acc += xv * (double)ep[d];
        xacc += xv * xv;
    }
    float M  = (float)acc;
    float x2 = (float)xacc;
    float d2 = fmaf(-2.f, M, x2 + e2[c]);
    unsigned int u = __float_as_uint(d2);
    u = (u & 0x80000000u) ? ~u : (u | 0x80000000u);
    atomicMin(&pk[e], ((unsigned long long)u << 32) | (unsigned int)c);
}

// ---------------------------------------------------------------------------
// rfinal: write winners. grid 64 x 256
__global__ void k_rfinal(const int* __restrict__ rlist, const int* __restrict__ rcnt,
                         const unsigned long long* __restrict__ pk,
                         int* __restrict__ idx_ws) {
    int e = blockIdx.x * 256 + threadIdx.x;
    const int cnt0 = *rcnt;
    const int cnt = cnt0 < NCAP ? cnt0 : NCAP;
    if (e < cnt) idx_ws[rlist[e]] = (int)(pk[e] & 0xFFFFFFFFull);
}

// ---------------------------------------------------------------------------
// out: quantized rows, index output, loss, histogram. One fp64 atomic/block.
// grid 1024 x 256
__launch_bounds__(256)
__global__ void k_out(const float* __restrict__ X, const float* __restrict__ E,
                      const int* __restrict__ idx_ws, float* __restrict__ out,
                      int* __restrict__ counts, double* __restrict__ loss) {
    const int tid = threadIdx.x;
    const int w = tid >> 6, lane = tid & 63;
    const int rbase = blockIdx.x * 64;
    double ls = 0.0;
    #pragma unroll 4
    for (int it = 0; it < 16; ++it) {
        const int row = rbase + it * 4 + w;
        const int k = idx_ws[row];
        float4 q = ((const float4*)(E + (size_t)k * DIM))[lane];
        float4 x = ((const float4*)(X + (size_t)row * DIM))[lane];
        ((float4*)(out + (size_t)row * DIM))[lane] = q;
        double d0 = (double)q.x - (double)x.x;
        double d1 = (double)q.y - (double)x.y;
        double d2 = (double)q.z - (double)x.z;
        double d3 = (double)q.w - (double)x.w;
        ls += d0 * d0 + d1 * d1 + d2 * d2 + d3 * d3;
        if (lane == 0) {
            atomicAdd(&counts[k], 1);
            out[OUT_IDX + row] = (float)k;
        }
    }
    __shared__ double red[256];
    red[tid] = ls;
    __syncthreads();
    for (int s = 128; s > 0; s >>= 1) {
        if (tid < s) red[tid] += red[tid + s];
        __syncthreads();
    }
    if (tid == 0) atomicAdd(loss, red[0]);
}

// ---------------------------------------------------------------------------
// fin: scalars
__global__ void k_fin(const int* __restrict__ counts, const double* __restrict__ loss,
                      float* __restrict__ out) {
    int t = threadIdx.x;
    __shared__ double red[256];
    double h = 0.0;
    #pragma unroll
    for (int i = 0; i < 4; ++i) {
        double p = (double)counts[t + i * 256] / (double)N_ROWS;
        h += p * log(p + 1e-10);
    }
    red[t] = h;
    __syncthreads();
    for (int s = 128; s > 0; s >>= 1) {
        if (t < s) red[t] += red[t + s];
        __syncthreads();
    }
    if (t == 0) {
        out[OUT_PERP] = (float)exp(-red[0]);
        out[OUT_LOSS] = (float)((*loss) / (double)Q_SIZE * 1.25);
    }
}

// ---------------------------------------------------------------------------
extern "C" void kernel_launch(void* const* d_in, const int* in_sizes, int n_in,
                              void* d_out, int out_size, void* d_ws, size_t ws_size,
                              hipStream_t stream) {
    (void)in_sizes; (void)n_in; (void)out_size; (void)ws_size;
    const float* X = (const float*)d_in[0];
    const float* E = (const float*)d_in[1];
    float* out = (float*)d_out;
    char* ws = (char*)d_ws;

    double*             loss   = (double*)(ws + WS_LOSS);
    int*                rcnt   = (int*)(ws + WS_RCNT);
    float*              e2     = (float*)(ws + WS_E2);
    float*              e2p    = (float*)(ws + WS_E2P);
    int*                counts = (int*)(ws + WS_COUNTS);
    int*                idx_ws = (int*)(ws + WS_IDX);
    int*                rlist  = (int*)(ws + WS_RLIST);
    float*              Et     = (float*)(ws + WS_ET);
    _Float16*           Pp     = (_Float16*)(ws + WS_P);
    int*                ncand  = (int*)(ws + WS_NCAND);
    unsigned long long* pk     = (unsigned long long*)(ws + WS_PK);
    int*                cand   = (int*)(ws + WS_CAND);

    k_prep<<<1024, 256, 0, stream>>>(E, e2, e2p, Et, Pp, counts, loss, rcnt);
    k_main<<<N_ROWS / RPB, 256, 0, stream>>>(X, Pp, e2p, idx_ws, rlist, rcnt);
    k_rprune<<<1024, 256, 0, stream>>>(X, Et, e2, rlist, rcnt, ncand, cand, pk);
    k_rexact<<<512, 256, 0, stream>>>(X, E, e2, rlist, rcnt, ncand, cand, pk);
    k_rfinal<<<64, 256, 0, stream>>>(rlist, rcnt, pk, idx_ws);
    k_out<<<1024, 256, 0, stream>>>(X, E, idx_ws, out, counts, loss);
    k_fin<<<1, 256, 0, stream>>>(counts, loss, out);
}